// Round 10
// baseline (66374.860 us; speedup 1.0000x reference)
//
#include <hip/hip_runtime.h>
#include <hip/hip_fp16.h>
#include <stdint.h>

#define SEQ_LEN 16384
#define H       512
#define NWG     16      // WG k owns h[32k..32k+32)
#define HK      32
#define T       512
#define NR      96      // rows per matrix per WG (3 gates x 32)
#define WPITCH  257     // uint32 pitch per W_ih row in LDS (256 data + 1 pad)

typedef unsigned long long u64;

#define LD_AG(p)   __hip_atomic_load((p),      __ATOMIC_RELAXED, __HIP_MEMORY_SCOPE_AGENT)
#define ST_AG(p,v) __hip_atomic_store((p),(v), __ATOMIC_RELAXED, __HIP_MEMORY_SCOPE_AGENT)

// exchange word: [f16 value (hi 16) | step tag (lo 16)]
__global__ void gru_init(uint32_t* __restrict__ tag32) {
    int i = blockIdx.x * blockDim.x + threadIdx.x;
    if (i < H)            ST_AG(&tag32[i], 0u);        // h0 = 0, tag 0
    else if (i < 2 * H)   ST_AG(&tag32[i], 0xFFFFu);   // invalid tag
}

__launch_bounds__(T, 1)
__global__ void gru_main(const float* __restrict__ x,
                         const float* __restrict__ Wih,
                         const float* __restrict__ Whh,
                         const float* __restrict__ bih,
                         const float* __restrict__ bhh,
                         float* __restrict__ out,
                         uint32_t* __restrict__ tag32)
{
    const int wg  = blockIdx.x;
    const int tid = threadIdx.x;
    const int j0  = wg * HK;

    __shared__ uint32_t w_lds[NR * WPITCH];      // W_ih slice only (f16 pairs)
    __shared__ float    x_lds[H];
    __shared__ float    h_lds[H];
    __shared__ float    sums_g[NR];
    __shared__ float    sums_h[NR];
    __shared__ float    bsum_g[NR];
    __shared__ float    bsum_h[NR];

    __half* wh = (__half*)w_lds;                 // half pitch = 2*WPITCH

    // ---- prologue: stage W_ih f32 -> f16 LDS ----
    for (int idx = tid; idx < NR * H; idx += T) {
        int r  = idx >> 9;                       // 0..95
        int k  = idx & (H - 1);
        int g  = r >> 5;
        int jj = r & 31;
        int grow = g * H + j0 + jj;
        wh[r * (2 * WPITCH) + k] = __float2half(Wih[(size_t)grow * H + k]);
    }
    if (tid < NR) {
        int g  = tid >> 5;
        int jj = tid & 31;
        int grow = g * H + j0 + jj;
        bsum_g[tid] = (g == 2) ? bih[grow] : (bih[grow] + bhh[grow]);
        bsum_h[tid] = (g == 2) ? bhh[grow] : 0.0f;
    }
    if (tid < 128)                               // prefill x_0
        ((float4*)x_lds)[tid] = ((const float4*)x)[tid];

    // ---- hh mapping (tid<384): row pair (hr, hr+48), chunk c8; weights -> regs ----
    const int wv = tid >> 6;                     // wave 0..5 valid
    const int r8 = (tid & 63) >> 3;
    const int c8 = tid & 7;
    const int hr = 8 * wv + r8;                  // 0..47
    uint32_t wreg[2][32];
    if (tid < 384) {
        #pragma unroll
        for (int p = 0; p < 2; ++p) {
            int rr   = hr + 48 * p;              // 0..95
            int g    = rr >> 5;
            int jj   = rr & 31;
            const float* Wr = Whh + (size_t)(g * H + j0 + jj) * H;
            #pragma unroll
            for (int i = 0; i < 32; ++i) {
                int cp = c8 * 32 + ((i + 4 * c8) & 31);    // col-pair, pre-staggered
                wreg[p][i] = (uint32_t)__half_as_ushort(__float2half(Wr[2 * cp])) |
                             ((uint32_t)__half_as_ushort(__float2half(Wr[2 * cp + 1])) << 16);
            }
        }
    }

    // gi mapping (tid>=128): row pair (gr, gr+48), chunk c8 (W_ih from LDS)
    const int gr = (tid - 128) >> 3;             // 0..47

    float4 xp, xq;
    if (tid < 128) xp = ((const float4*)(x + H))[tid];   // x_1
    float hprev = 0.0f;                          // own h (tid 0..31, exact f32)
    __syncthreads();

    for (int t = 0; t < SEQ_LEN; ++t) {
        const int par = t & 1, nxt = par ^ 1;

        if (tid < 128) {
            // issue x_{t+2} prefetch (hidden under the spin)
            int tq = t + 2; if (tq >= SEQ_LEN) tq = SEQ_LEN - 1;
            xq = ((const float4*)(x + (size_t)tq * H))[tid];

            // ---- tight agent-scope spin, both u64s issued per iteration ----
            const uint32_t need = (uint32_t)t & 0xFFFFu;
            const u64 want = (u64)need * 0x0000000100000001ull;
            const u64 M    = 0x0000FFFF0000FFFFull;
            u64* base = (u64*)(tag32 + (size_t)par * H) + 2 * tid;
            u64 va = LD_AG(base), vb = LD_AG(base + 1);
            while (((va & M) != want) | ((vb & M) != want)) {
                va = LD_AG(base); vb = LD_AG(base + 1);
            }
            int e = 4 * tid;
            h_lds[e]     = __half2float(__ushort_as_half((unsigned short)(va >> 16)));
            h_lds[e + 1] = __half2float(__ushort_as_half((unsigned short)(va >> 48)));
            h_lds[e + 2] = __half2float(__ushort_as_half((unsigned short)(vb >> 16)));
            h_lds[e + 3] = __half2float(__ushort_as_half((unsigned short)(vb >> 48)));
        } else {
            // ---- gi dots: rows gr, gr+48 over x_lds (W_ih from LDS) ----
            const uint32_t* w0 = w_lds + gr * WPITCH + c8 * 32;
            const uint32_t* w1 = w_lds + (gr + 48) * WPITCH + c8 * 32;
            const float2*   B  = (const float2*)(x_lds + c8 * 64);
            float a0 = 0.0f, a1 = 0.0f;
            #pragma unroll
            for (int i = 0; i < 32; ++i) {
                int s = (i + 4 * c8) & 31;
                float2 b  = B[s];
                float2 f0 = __half22float2(*(__half2*)&w0[s]);
                float2 f1 = __half22float2(*(__half2*)&w1[s]);
                a0 = fmaf(f0.x, b.x, fmaf(f0.y, b.y, a0));
                a1 = fmaf(f1.x, b.x, fmaf(f1.y, b.y, a1));
            }
            a0 += __shfl_xor(a0, 1); a1 += __shfl_xor(a1, 1);
            a0 += __shfl_xor(a0, 2); a1 += __shfl_xor(a1, 2);
            a0 += __shfl_xor(a0, 4); a1 += __shfl_xor(a1, 4);
            if (c8 == 0) {
                sums_g[gr]      = a0 + bsum_g[gr];
                sums_g[gr + 48] = a1 + bsum_g[gr + 48];
            }
        }
        __syncthreads();   // A: h_lds + sums_g ready

        if (tid < 384) {
            if (tid < 128) {
                ((float4*)x_lds)[tid] = xp;      // commit x_{t+1} (current xp!)
                xp = xq;                         // THEN advance the pipeline
            }
            // ---- hh dots: rows hr, hr+48 over h_lds (weights from registers) ----
            const float2* B = (const float2*)(h_lds + c8 * 64);
            float a0 = 0.0f, a1 = 0.0f;
            #pragma unroll
            for (int i = 0; i < 32; ++i) {
                int s = (i + 4 * c8) & 31;
                float2 b  = B[s];
                float2 f0 = __half22float2(*(__half2*)&wreg[0][i]);
                float2 f1 = __half22float2(*(__half2*)&wreg[1][i]);
                a0 = fmaf(f0.x, b.x, fmaf(f0.y, b.y, a0));
                a1 = fmaf(f1.x, b.x, fmaf(f1.y, b.y, a1));
            }
            a0 += __shfl_xor(a0, 1); a1 += __shfl_xor(a1, 1);
            a0 += __shfl_xor(a0, 2); a1 += __shfl_xor(a1, 2);
            a0 += __shfl_xor(a0, 4); a1 += __shfl_xor(a1, 4);
            if (c8 == 0) {
                sums_h[hr]      = a0 + bsum_h[hr];
                sums_h[hr + 48] = a1 + bsum_h[hr + 48];
            }
        }
        __syncthreads();   // B: sums_h + x_lds(t+1) ready

        if (tid < HK) {
            // ---- gates + publish (lanes 0..31 of wave 0) ----
            float sg0 = sums_g[tid], sg1 = sums_g[32 + tid], sg2 = sums_g[64 + tid];
            float sh0 = sums_h[tid], sh1 = sums_h[32 + tid], sh2 = sums_h[64 + tid];
            float r_ = 1.0f / (1.0f + __expf(-(sg0 + sh0)));
            float z_ = 1.0f / (1.0f + __expf(-(sg1 + sh1)));
            float a  = sg2 + r_ * sh2;
            a = fminf(12.0f, fmaxf(-12.0f, a));
            float e2 = __expf(2.0f * a);
            float n_ = (e2 - 1.0f) / (e2 + 1.0f);
            float hnew = (1.0f - z_) * n_ + z_ * hprev;
            hprev = hnew;
            uint32_t pk = ((uint32_t)__half_as_ushort(__float2half(hnew)) << 16)
                        | ((uint32_t)(t + 1) & 0xFFFFu);
            uint32_t hi = __shfl_xor(pk, 1);             // neighbor's word
            if ((tid & 1) == 0) {                        // 16 u64 stores per WG
                u64* pb = (u64*)(tag32 + (size_t)nxt * H + j0) + (tid >> 1);
                ST_AG(pb, ((u64)hi << 32) | (u64)pk);
            }
            out[(size_t)t * H + j0 + tid] = hnew;        // off critical path
        }
        __syncthreads();   // C: sums consumed; LDS safe to rewrite
    }
}

extern "C" void kernel_launch(void* const* d_in, const int* in_sizes, int n_in,
                              void* d_out, int out_size, void* d_ws, size_t ws_size,
                              hipStream_t stream) {
    const float* x   = (const float*)d_in[0];
    const float* Wih = (const float*)d_in[1];
    const float* Whh = (const float*)d_in[2];
    const float* bih = (const float*)d_in[3];
    const float* bhh = (const float*)d_in[4];
    float* out = (float*)d_out;
    uint32_t* tag32 = (uint32_t*)d_ws;           // 4 KB exchange

    gru_init<<<2, 512, 0, stream>>>(tag32);
    gru_main<<<NWG, T, 0, stream>>>(x, Wih, Whh, bih, bhh, out, tag32);
}

// Round 11
// 28307.855 us; speedup vs baseline: 2.3448x; 2.3448x over previous
//
#include <hip/hip_runtime.h>
#include <hip/hip_fp16.h>
#include <stdint.h>

#define SEQ_LEN 16384
#define H       512
#define NWG     32      // WG k owns h[16k..16k+16)
#define HK      16
#define T       512
#define NR      48      // rows per matrix per WG (3 gates x 16)
#define WPITCH  257     // uint32 pitch per weight row (256 data + 1 pad)

typedef unsigned long long u64;
typedef _Float16 h2 __attribute__((ext_vector_type(2)));

#define LD_AG(p)   __hip_atomic_load((p),      __ATOMIC_RELAXED, __HIP_MEMORY_SCOPE_AGENT)
#define ST_AG(p,v) __hip_atomic_store((p),(v), __ATOMIC_RELAXED, __HIP_MEMORY_SCOPE_AGENT)

__device__ __forceinline__ h2 as_h2(uint32_t u) {
    union { uint32_t u; h2 h; } c; c.u = u; return c.h;
}

#if defined(__has_builtin)
#if __has_builtin(__builtin_amdgcn_fdot2)
#define FDOT2(a, b, c) __builtin_amdgcn_fdot2((a), (b), (c), false)
#endif
#endif
#ifndef FDOT2
__device__ __forceinline__ float fdot2_sw(h2 a, h2 b, float c) {
    return fmaf((float)a.x, (float)b.x, fmaf((float)a.y, (float)b.y, c));
}
#define FDOT2(a, b, c) fdot2_sw((a), (b), (c))
#endif

__device__ __forceinline__ uint32_t pk2(float a, float b) {
    return (uint32_t)__half_as_ushort(__float2half(a)) |
           ((uint32_t)__half_as_ushort(__float2half(b)) << 16);
}

// exchange word: [f16 value (hi 16) | step tag (lo 16)]
__global__ void gru_init(uint32_t* __restrict__ tag32) {
    int i = blockIdx.x * blockDim.x + threadIdx.x;
    if (i < H)            ST_AG(&tag32[i], 0u);        // h0 = 0, tag 0
    else if (i < 2 * H)   ST_AG(&tag32[i], 0xFFFFu);   // invalid tag
}

__launch_bounds__(T, 1)
__global__ void gru_main(const float* __restrict__ x,
                         const float* __restrict__ Wih,
                         const float* __restrict__ Whh,
                         const float* __restrict__ bih,
                         const float* __restrict__ bhh,
                         float* __restrict__ out,
                         uint32_t* __restrict__ tag32)
{
    const int wg  = blockIdx.x;
    const int tid = threadIdx.x;
    const int j0  = wg * HK;

    __shared__ uint32_t w_lds[2 * NR * WPITCH];  // rows 0..47 W_ih, 48..95 W_hh (f16 pairs)
    __shared__ uint32_t x_u[2][H / 2];           // packed f16x2 x
    __shared__ uint32_t h_u[2][H / 2];           // packed f16x2 h
    __shared__ float    sums_g[2][NR];
    __shared__ float    sums_h[2][NR];
    __shared__ float    bsum_g[NR];
    __shared__ float    bsum_h[NR];

    __half* wh = (__half*)w_lds;                 // half pitch = 2*WPITCH

    // ---- prologue: stage weights f32 -> f16 LDS ----
    for (int idx = tid; idx < 2 * NR * H; idx += T) {
        int r  = idx >> 9;                       // 0..95
        int k  = idx & (H - 1);
        int rr = (r < NR) ? r : r - NR;
        int g  = rr >> 4;
        int jj = rr & 15;
        int grow = g * H + j0 + jj;
        float w = (r < NR) ? Wih[(size_t)grow * H + k] : Whh[(size_t)grow * H + k];
        wh[r * (2 * WPITCH) + k] = __float2half(w);
    }
    if (tid < NR) {
        int g  = tid >> 4;
        int jj = tid & 15;
        int grow = g * H + j0 + jj;
        bsum_g[tid] = (g == 2) ? bih[grow] : (bih[grow] + bhh[grow]);
        bsum_h[tid] = (g == 2) ? bhh[grow] : 0.0f;
    }
    if (tid < 128) {                             // prefill x_0 (packed f16)
        float4 x0 = ((const float4*)x)[tid];
        ((uint2*)x_u[0])[tid] = make_uint2(pk2(x0.x, x0.y), pk2(x0.z, x0.w));
    }
    __syncthreads();

    // dot-thread mapping (waves 2..7): row 0..47, chunk 0..7
    const int idxd = tid - 128;
    const int row  = idxd >> 3;                  // 0..47
    const int c8   = idxd & 7;                   // == tid&7

    // ---- W_hh into registers, pre-staggered so loop indices are static ----
    uint32_t wreg[32];
    if (tid >= 128) {
        const uint32_t* wr = w_lds + (NR + row) * WPITCH + c8 * 32;
        #pragma unroll
        for (int i = 0; i < 32; ++i) wreg[i] = wr[(i + 4 * c8) & 31];
    }
    __syncthreads();

    float4 xp;
    if (tid < 128) xp = ((const float4*)(x + H))[tid];   // x_1
    float hprev = 0.0f;                          // own h (wave-2 lanes 0..15)

    for (int t = 0; t < SEQ_LEN; ++t) {
        const int par = t & 1, nxt = par ^ 1;

        if (tid < 128) {
            // issue x_{t+2} prefetch (hidden under the spin)
            int tq = t + 2; if (tq >= SEQ_LEN) tq = SEQ_LEN - 1;
            float4 xq = ((const float4*)(x + (size_t)tq * H))[tid];

            // ---- champion tight agent-scope spin on 4 words (2x u64) ----
            const uint32_t need = (uint32_t)t & 0xFFFFu;
            const u64 want = (u64)need * 0x0000000100000001ull;
            const u64 M    = 0x0000FFFF0000FFFFull;
            u64* base = (u64*)(tag32 + (size_t)par * H) + 2 * tid;
            u64 va, vb;
            do { va = LD_AG(base);     } while ((va & M) != want);
            do { vb = LD_AG(base + 1); } while ((vb & M) != want);
            // strip tags -> packed f16 pairs (pure bit ops, no cvt)
            uint32_t p0 = (uint32_t)((va >> 16) & 0xFFFFu) | ((uint32_t)(va >> 48) << 16);
            uint32_t p1 = (uint32_t)((vb >> 16) & 0xFFFFu) | ((uint32_t)(vb >> 48) << 16);
            ((uint2*)h_u[par])[tid] = make_uint2(p0, p1);

            __syncthreads();   // A: h_u[par] + sums_g[par] ready
            // commit x_{t+1} as packed f16 (off critical path for dotters)
            ((uint2*)x_u[nxt])[tid] = make_uint2(pk2(xp.x, xp.y), pk2(xp.z, xp.w));
            xp = xq;
            __syncthreads();   // B: sums_h[par] + x_u[nxt] ready
            // pollers immediately proceed to next step's spin
        } else {
            // ---- gi dots over x_u[par] (weights from LDS, fdot2) ----
            {
                const uint32_t* gw = w_lds + row * WPITCH + c8 * 32;
                const uint32_t* B  = &x_u[par][c8 * 32];
                float acc = 0.0f;
                #pragma unroll
                for (int i = 0; i < 32; ++i) {
                    int s = (i + 4 * c8) & 31;
                    acc = FDOT2(as_h2(gw[s]), as_h2(B[s]), acc);
                }
                acc += __shfl_xor(acc, 1);
                acc += __shfl_xor(acc, 2);
                acc += __shfl_xor(acc, 4);
                if (c8 == 0) sums_g[par][row] = acc + bsum_g[row];
            }
            __syncthreads();   // A

            // ---- hh dots over h_u[par] (weights from registers, fdot2) ----
            {
                const uint32_t* B = &h_u[par][c8 * 32];
                float acc = 0.0f;
                #pragma unroll
                for (int i = 0; i < 32; ++i) {
                    int s = (i + 4 * c8) & 31;
                    acc = FDOT2(as_h2(wreg[i]), as_h2(B[s]), acc);
                }
                acc += __shfl_xor(acc, 1);
                acc += __shfl_xor(acc, 2);
                acc += __shfl_xor(acc, 4);
                if (c8 == 0) sums_h[par][row] = acc + bsum_h[row];
            }
            __syncthreads();   // B

            // ---- gates + publish: wave 2 only (lanes 0..15 compute, 0..7 store u64) ----
            if (tid < 192) {
                int j = tid & 63;
                uint32_t pk = 0;
                float hnew = 0.0f;
                if (j < 16) {
                    float sg0 = sums_g[par][j],      sg1 = sums_g[par][16 + j], sg2 = sums_g[par][32 + j];
                    float sh0 = sums_h[par][j],      sh1 = sums_h[par][16 + j], sh2 = sums_h[par][32 + j];
                    float r_ = 1.0f / (1.0f + __expf(-(sg0 + sh0)));
                    float z_ = 1.0f / (1.0f + __expf(-(sg1 + sh1)));
                    float a  = sg2 + r_ * sh2;
                    a = fminf(12.0f, fmaxf(-12.0f, a));
                    float e2 = __expf(2.0f * a);
                    float n_ = (e2 - 1.0f) / (e2 + 1.0f);
                    hnew = (1.0f - z_) * n_ + z_ * hprev;
                    hprev = hnew;
                    pk = ((uint32_t)__half_as_ushort(__float2half(hnew)) << 16)
                       | ((uint32_t)(t + 1) & 0xFFFFu);
                }
                uint32_t lo = __shfl(pk, 2 * (j & 31));
                uint32_t hi = __shfl(pk, 2 * (j & 31) + 1);
                if (j < 8) {
                    u64* pb = (u64*)(tag32 + (size_t)nxt * H) + wg * 8 + j;
                    ST_AG(pb, ((u64)hi << 32) | (u64)lo);
                }
                if (j < 16) out[(size_t)t * H + j0 + j] = hnew;
            }
            // wave 2 proceeds to next step's gi (lateness absorbed at barrier A)
        }
    }
}

extern "C" void kernel_launch(void* const* d_in, const int* in_sizes, int n_in,
                              void* d_out, int out_size, void* d_ws, size_t ws_size,
                              hipStream_t stream) {
    const float* x   = (const float*)d_in[0];
    const float* Wih = (const float*)d_in[1];
    const float* Whh = (const float*)d_in[2];
    const float* bih = (const float*)d_in[3];
    const float* bhh = (const float*)d_in[4];
    float* out = (float*)d_out;
    uint32_t* tag32 = (uint32_t*)d_ws;           // 4 KB exchange

    gru_init<<<2, 512, 0, stream>>>(tag32);
    gru_main<<<NWG, T, 0, stream>>>(x, Wih, Whh, bih, bhh, out, tag32);
}

// Round 12
// 26745.596 us; speedup vs baseline: 2.4817x; 1.0584x over previous
//
#include <hip/hip_runtime.h>
#include <hip/hip_fp16.h>
#include <stdint.h>

#define SEQ_LEN 16384
#define H       512
#define NWG     32      // WG k owns h[16k..16k+16)
#define HK      16
#define T       512
#define NR      48      // rows per matrix per WG (3 gates x 16)
#define WPITCH  257     // uint32 pitch per weight row (256 data + 1 pad)

typedef unsigned long long u64;
typedef _Float16 h2 __attribute__((ext_vector_type(2)));
typedef unsigned int u32x4 __attribute__((ext_vector_type(4)));

#define LD_AG(p)   __hip_atomic_load((p),      __ATOMIC_RELAXED, __HIP_MEMORY_SCOPE_AGENT)
#define ST_AG(p,v) __hip_atomic_store((p),(v), __ATOMIC_RELAXED, __HIP_MEMORY_SCOPE_AGENT)

__device__ __forceinline__ h2 as_h2(uint32_t u) {
    union { uint32_t u; h2 h; } c; c.u = u; return c.h;
}

#if defined(__has_builtin)
#if __has_builtin(__builtin_amdgcn_fdot2)
#define FDOT2(a, b, c) __builtin_amdgcn_fdot2((a), (b), (c), false)
#endif
#endif
#ifndef FDOT2
__device__ __forceinline__ float fdot2_sw(h2 a, h2 b, float c) {
    return fmaf((float)a.x, (float)b.x, fmaf((float)a.y, (float)b.y, c));
}
#define FDOT2(a, b, c) fdot2_sw((a), (b), (c))
#endif

__device__ __forceinline__ uint32_t pk2(float a, float b) {
    return (uint32_t)__half_as_ushort(__float2half(a)) |
           ((uint32_t)__half_as_ushort(__float2half(b)) << 16);
}

// one 16B load covering 4 tagged words; sc0+sc1 = bypass L1+L2 (agent visibility,
// matches atomic path; R7 measured sc0-only stales in local L2)
__device__ __forceinline__ u32x4 poll16(const uint32_t* p) {
    u32x4 v;
    asm volatile("global_load_dwordx4 %0, %1, off sc0 sc1\n\t"
                 "s_waitcnt vmcnt(0)"
                 : "=v"(v) : "v"(p) : "memory");
    return v;
}

// exchange word: [f16 value (hi 16) | step tag (lo 16)]
__global__ void gru_init(uint32_t* __restrict__ tag32) {
    int i = blockIdx.x * blockDim.x + threadIdx.x;
    if (i < H)            ST_AG(&tag32[i], 0u);        // h0 = 0, tag 0
    else if (i < 2 * H)   ST_AG(&tag32[i], 0xFFFFu);   // invalid tag
}

__launch_bounds__(T, 1)
__global__ void gru_main(const float* __restrict__ x,
                         const float* __restrict__ Wih,
                         const float* __restrict__ Whh,
                         const float* __restrict__ bih,
                         const float* __restrict__ bhh,
                         float* __restrict__ out,
                         uint32_t* __restrict__ tag32)
{
    const int wg  = blockIdx.x;
    const int tid = threadIdx.x;
    const int j0  = wg * HK;

    __shared__ uint32_t w_lds[2 * NR * WPITCH];  // rows 0..47 W_ih, 48..95 W_hh (f16 pairs)
    __shared__ uint32_t x_u[2][H / 2];           // packed f16x2 x
    __shared__ uint32_t h_u[2][H / 2];           // packed f16x2 h
    __shared__ float    sums_g[2][NR];
    __shared__ float    sums_h[2][NR];
    __shared__ float    bsum_g[NR];
    __shared__ float    bsum_h[NR];

    __half* wh = (__half*)w_lds;                 // half pitch = 2*WPITCH

    // ---- prologue: stage weights f32 -> f16 LDS ----
    for (int idx = tid; idx < 2 * NR * H; idx += T) {
        int r  = idx >> 9;                       // 0..95
        int k  = idx & (H - 1);
        int rr = (r < NR) ? r : r - NR;
        int g  = rr >> 4;
        int jj = rr & 15;
        int grow = g * H + j0 + jj;
        float w = (r < NR) ? Wih[(size_t)grow * H + k] : Whh[(size_t)grow * H + k];
        wh[r * (2 * WPITCH) + k] = __float2half(w);
    }
    if (tid < NR) {
        int g  = tid >> 4;
        int jj = tid & 15;
        int grow = g * H + j0 + jj;
        bsum_g[tid] = (g == 2) ? bih[grow] : (bih[grow] + bhh[grow]);
        bsum_h[tid] = (g == 2) ? bhh[grow] : 0.0f;
    }
    if (tid < 128) {                             // prefill x_0 (packed f16)
        float4 x0 = ((const float4*)x)[tid];
        ((uint2*)x_u[0])[tid] = make_uint2(pk2(x0.x, x0.y), pk2(x0.z, x0.w));
    }
    __syncthreads();

    // dot-thread mapping (waves 2..7): row 0..47, chunk 0..7
    const int idxd = tid - 128;
    const int row  = idxd >> 3;                  // 0..47
    const int c8   = idxd & 7;                   // == tid&7

    // ---- W_hh into registers, pre-staggered so loop indices are static ----
    uint32_t wreg[32];
    if (tid >= 128) {
        const uint32_t* wr = w_lds + (NR + row) * WPITCH + c8 * 32;
        #pragma unroll
        for (int i = 0; i < 32; ++i) wreg[i] = wr[(i + 4 * c8) & 31];
    }
    __syncthreads();

    float4 xp;
    if (tid < 128) xp = ((const float4*)(x + H))[tid];   // x_1
    float hprev = 0.0f;                          // own h (wave-2 lanes 0..15)

    for (int t = 0; t < SEQ_LEN; ++t) {
        const int par = t & 1, nxt = par ^ 1;

        if (tid < 128) {
            // issue x_{t+2} prefetch (hidden under the spin)
            int tq = t + 2; if (tq >= SEQ_LEN) tq = SEQ_LEN - 1;
            float4 xq = ((const float4*)(x + (size_t)tq * H))[tid];

            // ---- single dwordx4 tight spin on 4 tagged words ----
            const uint32_t need = (uint32_t)t & 0xFFFFu;
            const uint32_t* base = tag32 + (size_t)par * H + 4 * tid;
            u32x4 v = poll16(base);
            while ((((v[0] ^ need) | (v[1] ^ need)) |
                    ((v[2] ^ need) | (v[3] ^ need))) & 0xFFFFu)
                v = poll16(base);
            // strip tags -> packed f16 pairs (pure bit ops)
            uint32_t p0 = (v[0] >> 16) | (v[1] & 0xFFFF0000u);
            uint32_t p1 = (v[2] >> 16) | (v[3] & 0xFFFF0000u);
            ((uint2*)h_u[par])[tid] = make_uint2(p0, p1);

            __syncthreads();   // A: h_u[par] + sums_g[par] ready
            // commit x_{t+1} as packed f16 (off critical path for dotters)
            ((uint2*)x_u[nxt])[tid] = make_uint2(pk2(xp.x, xp.y), pk2(xp.z, xp.w));
            xp = xq;
            __syncthreads();   // B: sums_h[par] + x_u[nxt] ready
            // pollers immediately proceed to next step's spin
        } else {
            // ---- gi dots over x_u[par] (weights from LDS, fdot2) ----
            {
                const uint32_t* gw = w_lds + row * WPITCH + c8 * 32;
                const uint32_t* B  = &x_u[par][c8 * 32];
                float acc = 0.0f;
                #pragma unroll
                for (int i = 0; i < 32; ++i) {
                    int s = (i + 4 * c8) & 31;
                    acc = FDOT2(as_h2(gw[s]), as_h2(B[s]), acc);
                }
                acc += __shfl_xor(acc, 1);
                acc += __shfl_xor(acc, 2);
                acc += __shfl_xor(acc, 4);
                if (c8 == 0) sums_g[par][row] = acc + bsum_g[row];
            }
            __syncthreads();   // A

            // ---- hh dots over h_u[par] (weights from registers, fdot2) ----
            {
                const uint32_t* B = &h_u[par][c8 * 32];
                float acc = 0.0f;
                #pragma unroll
                for (int i = 0; i < 32; ++i) {
                    int s = (i + 4 * c8) & 31;
                    acc = FDOT2(as_h2(wreg[i]), as_h2(B[s]), acc);
                }
                acc += __shfl_xor(acc, 1);
                acc += __shfl_xor(acc, 2);
                acc += __shfl_xor(acc, 4);
                if (c8 == 0) sums_h[par][row] = acc + bsum_h[row];
            }
            __syncthreads();   // B

            // ---- gates + publish: wave 2 only (lanes 0..15 compute, 0..7 store u64) ----
            if (tid < 192) {
                int j = tid & 63;
                uint32_t pk = 0;
                float hnew = 0.0f;
                if (j < 16) {
                    float sg0 = sums_g[par][j],      sg1 = sums_g[par][16 + j], sg2 = sums_g[par][32 + j];
                    float sh0 = sums_h[par][j],      sh1 = sums_h[par][16 + j], sh2 = sums_h[par][32 + j];
                    float r_ = 1.0f / (1.0f + __expf(-(sg0 + sh0)));
                    float z_ = 1.0f / (1.0f + __expf(-(sg1 + sh1)));
                    float a  = sg2 + r_ * sh2;
                    a = fminf(12.0f, fmaxf(-12.0f, a));
                    float e2 = __expf(2.0f * a);
                    float n_ = (e2 - 1.0f) / (e2 + 1.0f);
                    hnew = (1.0f - z_) * n_ + z_ * hprev;
                    hprev = hnew;
                    pk = ((uint32_t)__half_as_ushort(__float2half(hnew)) << 16)
                       | ((uint32_t)(t + 1) & 0xFFFFu);
                }
                uint32_t lo = __shfl(pk, 2 * (j & 31));
                uint32_t hi = __shfl(pk, 2 * (j & 31) + 1);
                if (j < 8) {
                    u64* pb = (u64*)(tag32 + (size_t)nxt * H) + wg * 8 + j;
                    ST_AG(pb, ((u64)hi << 32) | (u64)lo);
                }
                if (j < 16) out[(size_t)t * H + j0 + j] = hnew;
            }
            // wave 2 proceeds to next step's gi (lateness absorbed at barrier A)
        }
    }
}

extern "C" void kernel_launch(void* const* d_in, const int* in_sizes, int n_in,
                              void* d_out, int out_size, void* d_ws, size_t ws_size,
                              hipStream_t stream) {
    const float* x   = (const float*)d_in[0];
    const float* Wih = (const float*)d_in[1];
    const float* Whh = (const float*)d_in[2];
    const float* bih = (const float*)d_in[3];
    const float* bhh = (const float*)d_in[4];
    float* out = (float*)d_out;
    uint32_t* tag32 = (uint32_t*)d_ws;           // 4 KB exchange

    gru_init<<<2, 512, 0, stream>>>(tag32);
    gru_main<<<NWG, T, 0, stream>>>(x, Wih, Whh, bih, bhh, out, tag32);
}